// Round 15
// baseline (296.396 us; speedup 1.0000x reference)
//
#include <hip/hip_runtime.h>

// PGA G(3,0,1) GeometricBilinear — R15: de-fused 3-kernel pipeline.
// P=16384, CIN=64, 2H=256, H=128, COUT=64, 16 blades.
//
// Why de-fuse (R4-R14 post-mortem): the fused bilinear needs 128 acc + 64
// prod regs per wave -> ~240 regs -> hard 2 waves/SIMD in every variant ->
// exposed weight-load latency; measured ~98k cyc/block vs ~25k modeled.
// De-fused kernels are low-reg (acc<=16 f32x4), weights are LDS-resident
// (loaded ONCE per block, no global loads in MFMA loops), and the per-kernel
// rocprof rows decompose where time actually goes.
//   K1 gemm1: grid (pos-tile 128 x e-pair 8): h[p][j][ch] bf16 bounce.
//     flipped MFMA (A=X rows=pos, B=W cols=ch; D: col ln=ch, row lh*4+r=pos
//     — orientation verified by R13 pass). W slice (98KB) in LDS.
//   K2 prod: stage h-tile(16 pos,128KB) -> per-(pos,cc) products (verified
//     gp/jn tables) -> out2[p][cc][j] bf16.
//   K3 gemm2: grid (pos-tile 16 x o-tile 16): transpose-stage out2 to
//     [e2][pos][k2] rows, W2 in 2 LDS halves, coalesced fp32 out stores.
// Run in 4 position-quarters so h (33.5MB) + out2 (16.8MB) stay L3-hot and
// ws fits: 786KB(w1c)+393KB(w2c)+33.6+16.8 = 51.6MB < known-available 65.6MB.
// Weight packing reuses R11's verified prep_w_c (w1c[o][1536], w2c[o][3072]).

namespace {

constexpr int popc4(int v){int c=0;while(v){c+=v&1;v>>=1;}return c;}
constexpr float sgnf(int a,int b){int s=0;a>>=1;while(a){s+=popc4(a&b);a>>=1;}return (s&1)?-1.f:1.f;}

struct Tabs { float gp[16][16]; float jn[16][16]; };
constexpr Tabs mk(){
    Tabs t{};
    for(int a=0;a<16;a++)for(int b=0;b<16;b++){
        t.gp[a][b] = (a&b&1) ? 0.f : sgnf(a,b);
        if((a|b)==15){
            const int k = a&b;
            t.jn[a][b] = sgnf(a,15^a)*sgnf(b,15^b)*sgnf(15^a,15^b)*sgnf(k,15^k);
        } else t.jn[a][b] = 0.f;
    }
    return t;
}
constexpr Tabs TB = mk();
constexpr int GE[8] = {0,1,1,2,1,2,2,3};  // f32 fallback

constexpr int W1C_ELEMS = 256*1536;
constexpr int W2C_ELEMS = 64*3072;
constexpr int QP = 4096;                       // positions per quarter
constexpr long H_ELEMS  = (long)QP*16*256;     // h quarter, bf16 [pos][j][ch]
constexpr long O2_ELEMS = (long)QP*128*16;     // out2 quarter, bf16 [pos][cc][j]

typedef short bf16x8 __attribute__((ext_vector_type(8)));
typedef float f32x4  __attribute__((ext_vector_type(4)));

__device__ inline unsigned short f2bf(float f){
    unsigned int u = __float_as_uint(f);
    u = u + 0x7fffu + ((u >> 16) & 1u);
    return (unsigned short)(u >> 16);
}
__device__ inline float bf2f(unsigned short h){
    unsigned int u = ((unsigned int)h) << 16;
    return __uint_as_float(u);
}

} // namespace

// ---------------- prep (verified R11): w1c[o][1536], w2c[o][3072] ------------
__global__ void prep_w_c(const float* __restrict__ w1, const float* __restrict__ w2,
                         unsigned short* __restrict__ w1c, unsigned short* __restrict__ w2c)
{
    int idx = blockIdx.x * 256 + threadIdx.x;
    if (idx < W1C_ELEMS) {
        const int o = idx / 1536, r = idx - o*1536;
        const int p = r / 192, q = r - p*192;
        float v;
        if (q < 64) {
            v = w1[(o*64 + q)*9 + popc4(2*p)];
        } else {
            const int j = 2*p + 1, k = q - 64, g = popc4(j);
            v = (k < 64) ? w1[(o*64 + k)*9 + g + 4]
                         : w1[(o*64 + (k - 64))*9 + g];
        }
        w1c[idx] = f2bf(v);
    } else {
        idx -= W1C_ELEMS;
        if (idx < W2C_ELEMS) {
            const int o = idx / 3072, r = idx - o*3072;
            const int p = r / 384, q = r - p*384;
            float v;
            if (q < 128) {
                v = w2[(o*128 + q)*9 + popc4(2*p)];
            } else {
                const int j = 2*p + 1, k = q - 128, g = popc4(j);
                v = (k < 128) ? w2[(o*128 + k)*9 + g + 4]
                              : w2[(o*128 + (k - 128))*9 + g];
            }
            w2c[idx] = f2bf(v);
        }
    }
}

// ================= K1: h[p][j][ch] for blade pair e ==========================
// grid = 32 pos-tiles(128) x 8 e;  512 thr (8 waves).
// LDS: X [128 pos][272B] (k=s*64+i, bytes s*128+i*2)  @0      (34816)
//      W [256 ch][400B]  (even-j 128B | odd-j 256B | pad) @34816 (102400)
__global__ __launch_bounds__(512, 1) void k1_gemm(
    const float* __restrict__ x, const float* __restrict__ b1,
    const unsigned short* __restrict__ w1c, unsigned short* __restrict__ hG,
    int P0)
{
    __shared__ __attribute__((aligned(16))) char LDS[137216];
    const int t  = threadIdx.x;
    const int e  = blockIdx.x & 7;
    const int pt = blockIdx.x >> 3;
    const int w  = t >> 6, l = t & 63, ln = l & 15, lh = l >> 4;
    const int cq = w >> 1, ph = w & 1;
    const int pbase = P0 + pt*128;

    // stage X: x[p][i][2e+s] -> LDS
    {
        const int pos = t >> 2, iq = t & 3;
        const float* gs = x + ((long)(pbase + pos))*1024 + (iq*16)*16 + 2*e;
        char* row = LDS + pos*272;
        #pragma unroll
        for (int u = 0; u < 16; ++u) {
            const float2 v = *(const float2*)(gs + u*16);
            const int i = iq*16 + u;
            *(unsigned short*)(row + i*2)        = f2bf(v.x);   // s=0
            *(unsigned short*)(row + 128 + i*2)  = f2bf(v.y);   // s=1
        }
    }
    // stage W: w1c[ch][e*192 .. +192) -> LDS [ch][400B]
    {
        char* WL = LDS + 34816;
        #pragma unroll
        for (int it = 0; it < 12; ++it) {
            const int cid = it*512 + t;            // 6144 chunks of 8 elems
            const int ch = cid / 24, kc = cid - ch*24;
            const bf16x8 v = *(const bf16x8*)(w1c + ch*1536 + e*192 + kc*8);
            *(bf16x8*)(WL + ch*400 + kc*16) = v;
        }
    }
    __syncthreads();

    const char* WL = LDS + 34816;
    #pragma unroll
    for (int jj = 0; jj < 2; ++jj) {               // 0: j=2e (K=64), 1: j=2e+1 (K=128)
        const int j = 2*e + jj;
        const int nkf = jj ? 4 : 2;
        const int wb = jj ? 128 : 0;
        #pragma unroll
        for (int nt = 0; nt < 4; ++nt) {
            const int ch = cq*64 + nt*16 + ln;
            const float bv = (e == 0 && jj == 0) ? b1[ch] : 0.f;
            #pragma unroll
            for (int mt = 0; mt < 4; ++mt) {
                f32x4 acc = (f32x4)0.f;
                const char* xrow = LDS + (ph*64 + mt*16 + ln)*272;
                const char* wrow = WL + ch*400 + wb;
                #pragma unroll
                for (int kf = 0; kf < nkf; ++kf) {
                    const bf16x8 a = *(const bf16x8*)(xrow + kf*64 + lh*16);
                    const bf16x8 b = *(const bf16x8*)(wrow + kf*64 + lh*16);
                    acc = __builtin_amdgcn_mfma_f32_16x16x32_bf16(a, b, acc, 0, 0, 0);
                }
                // D: col ln = ch (already in address), row lh*4+r = pos
                #pragma unroll
                for (int r = 0; r < 4; ++r) {
                    const int pos = ph*64 + mt*16 + lh*4 + r;
                    hG[(((long)(pbase + pos))*16 + j)*256 + ch] = f2bf(acc[r] + bv);
                }
            }
        }
    }
}

// ================= K2: products -> out2[p][cc][j] ============================
// grid = 256 blocks x 16 pos; 256 thr. LDS: h [pos][j][264] rows (528B).
__global__ __launch_bounds__(256, 1) void k2_prod(
    const unsigned short* __restrict__ hG, const float* __restrict__ ref,
    unsigned short* __restrict__ o2G, int P0)
{
    __shared__ __attribute__((aligned(16))) char LDS[135168];
    const int t = threadIdx.x;
    const int pbase = P0 + blockIdx.x * 16;

    // stage h-tile (128KB contiguous)
    #pragma unroll
    for (int it = 0; it < 32; ++it) {
        const int cid = it*256 + t;                // 8192 chunks of 8 elems
        const int pj = cid >> 5, ch = (cid & 31)*8;   // pj = pos*16+j
        const bf16x8 v = *(const bf16x8*)(hG + ((long)(pbase)*16 + pj)*256 + ch);
        *(bf16x8*)(LDS + pj*528 + ch*2) = v;
    }
    __syncthreads();

    const int pos = t >> 4, oct = t & 15;
    const float rv = ref[((long)(pbase + pos))*16 + 15];
    const char* hrow = LDS + pos*16*528;

    #pragma unroll 1
    for (int u = 0; u < 8; ++u) {
        const int cc = oct*8 + u;
        const int cA = (cc < 64) ? cc : cc + 64;
        const int cB = cA + 64;
        float lv[16], rvv[16];
        #pragma unroll
        for (int j = 0; j < 16; ++j) {
            lv[j]  = bf2f(*(const unsigned short*)(hrow + j*528 + cA*2));
            rvv[j] = bf2f(*(const unsigned short*)(hrow + j*528 + cB*2));
        }
        float prod[16];
        #pragma unroll
        for (int j = 0; j < 16; ++j) prod[j] = 0.f;
        if (cc < 64) {
            #pragma unroll
            for (int A = 0; A < 16; ++A)
                #pragma unroll
                for (int B = 0; B < 16; ++B) {
                    if (TB.gp[A][B] > 0.f)      prod[A ^ B] += lv[A] * rvv[B];
                    else if (TB.gp[A][B] < 0.f) prod[A ^ B] -= lv[A] * rvv[B];
                }
        } else {
            #pragma unroll
            for (int A = 0; A < 16; ++A)
                #pragma unroll
                for (int B = 0; B < 16; ++B) {
                    if (TB.jn[A][B] > 0.f)      prod[A & B] += lv[A] * rvv[B];
                    else if (TB.jn[A][B] < 0.f) prod[A & B] -= lv[A] * rvv[B];
                }
            #pragma unroll
            for (int j = 0; j < 16; ++j) prod[j] *= rv;
        }
        unsigned out[8];
        #pragma unroll
        for (int q = 0; q < 8; ++q)
            out[q] = (unsigned)f2bf(prod[2*q]) | ((unsigned)f2bf(prod[2*q+1]) << 16);
        unsigned short* gd = o2G + (((long)(pbase + pos))*128 + cc)*16;
        *(bf16x8*)(gd)     = *(bf16x8*)&out[0];
        *(bf16x8*)(gd + 8) = *(bf16x8*)&out[4];
    }
}

// ================= K3: out = equi_linear2(out2) ==============================
// grid = 256 pos-tiles(16) x 4 o-tiles(16); 256 thr (4 waves).
// LDS: X3 [e2*16+pos][528B] (k2=s*128+cc) @0 (67584); W half [o 16][3088B] @67584.
__global__ __launch_bounds__(256, 1) void k3_gemm(
    const unsigned short* __restrict__ o2G, const float* __restrict__ b2,
    const unsigned short* __restrict__ w2c, float* __restrict__ out, int P0)
{
    __shared__ __attribute__((aligned(16))) char LDS[117248];
    const int t = threadIdx.x;
    const int ot = blockIdx.x & 3;
    const int pt = blockIdx.x >> 2;
    const int w = t >> 6, l = t & 63, ln = l & 15, lh = l >> 4;
    const int pbase = P0 + pt*16;
    const int o0 = ot*16;

    // transpose-stage out2 [pos][cc][j] -> X3 [e2*16+pos][s*128+cc]
    #pragma unroll
    for (int it = 0; it < 16; ++it) {
        const int cid = it*256 + t;                // 4096 chunks
        const int jh = cid & 1, cc = (cid >> 1) & 127, pos = cid >> 8;
        const bf16x8 v = *(const bf16x8*)(o2G + (((long)(pbase + pos))*128 + cc)*16 + jh*8);
        #pragma unroll
        for (int u = 0; u < 8; ++u) {
            const int j = jh*8 + u, e2 = j >> 1, s = j & 1;
            *(unsigned short*)(LDS + (e2*16 + pos)*528 + (s*128 + cc)*2) = ((unsigned short*)&v)[u];
        }
    }

    f32x4 acc[4];
    #pragma unroll
    for (int a = 0; a < 4; ++a) acc[a] = (f32x4)0.f;

    #pragma unroll
    for (int hh = 0; hh < 2; ++hh) {     // W halves: e2 0..3, then 4..7
        // stage W half: w2c[o0+o][hh*1536 .. +1536) -> [o][3088B]
        __syncthreads();                 // X3 ready (hh=0) / prior half reads done
        {
            char* WL = LDS + 67584;
            #pragma unroll
            for (int it = 0; it < 12; ++it) {
                const int cid = it*256 + t;        // 3072 chunks of 8
                const int o = cid / 192, kc = cid - o*192;
                const bf16x8 v = *(const bf16x8*)(w2c + (o0 + o)*3072 + hh*1536 + kc*8);
                *(bf16x8*)(WL + o*3088 + kc*16) = v;
            }
        }
        __syncthreads();
        const char* WL = LDS + 67584;
        #pragma unroll
        for (int jj = 0; jj < 2; ++jj) {           // wave w: j2 = hh*8 + 2w + jj
            const int j2l = 2*w + jj;              // within half
            const int e2l = w;                     // e2' = w
            const int e2  = hh*4 + e2l;
            const int nkf = jj ? 8 : 4;
            const int wbyte = (e2l*384 + (jj ? 128 : 0))*2;
            f32x4 a4 = (f32x4)0.f;
            const char* xrow = LDS + (e2*16 + ln)*528;
            const char* wrow = WL + ln*3088 + wbyte;
            // NOTE: A lane ln = pos row; B lane ln = o col. Both read via own row.
            #pragma unroll
            for (int kf = 0; kf < nkf; ++kf) {
                const bf16x8 a = *(const bf16x8*)(xrow + kf*64 + lh*16);
                const bf16x8 b = *(const bf16x8*)(wrow + kf*64 + lh*16);
                a4 = __builtin_amdgcn_mfma_f32_16x16x32_bf16(a, b, a4, 0, 0, 0);
            }
            acc[hh*2 + jj] = a4;
        }
    }
    __syncthreads();   // all MFMA reads done; LDS reusable for epilogue

    // epilogue: acc -> LDS out-tile [pos][o 16][j 16] f32 (16KB @0)
    {
        const float bv = b2[o0 + ln];
        #pragma unroll
        for (int q = 0; q < 4; ++q) {
            const int j2 = (q >> 1)*8 + 2*w + (q & 1);
            #pragma unroll
            for (int r = 0; r < 4; ++r) {
                const int pos = lh*4 + r;
                float v = acc[q][r];
                if (j2 == 0) v += bv;
                *(float*)(LDS + ((pos*16 + ln)*16 + j2)*4) = v;
            }
        }
    }
    __syncthreads();
    #pragma unroll
    for (int it = 0; it < 4; ++it) {
        const int f = (it*256 + t)*4;              // f32 index in 4096-elem tile
        const int pos = f >> 8, rem = f & 255;
        const float4 v = *(const float4*)(LDS + f*4);
        *(float4*)(out + ((long)(pbase + pos))*1024 + o0*16 + rem) = v;
    }
}

// ================= fp32 last-resort fallback (verified R3) ===================
__global__ __launch_bounds__(256, 1) void gb_fused_f32(
    const float* __restrict__ x, const float* __restrict__ ref,
    const float* __restrict__ w1, const float* __restrict__ b1,
    const float* __restrict__ w2, const float* __restrict__ b2,
    float* __restrict__ out)
{
    __shared__ float lds[16384];
    __shared__ float lrefs[8];
    const int t = threadIdx.x;
    const int p0 = blockIdx.x * 8;
    {
        const float4* xg = reinterpret_cast<const float4*>(x) + (size_t)p0 * 256;
        float4* xl = reinterpret_cast<float4*>(lds);
        #pragma unroll
        for (int r = 0; r < 8; ++r) xl[r*256 + t] = xg[r*256 + t];
        if (t < 8) lrefs[t] = ref[(p0 + t)*16 + 15];
    }
    __syncthreads();
    const int c    = t & 127;
    const int half = t >> 7;
    const int ca   = (c < 64) ? c : (c + 64);
    const int cb   = ca + 64;
    float acc[4][2][16];
    #pragma unroll
    for (int q = 0; q < 4; ++q)
        #pragma unroll
        for (int s = 0; s < 2; ++s)
            #pragma unroll
            for (int j = 0; j < 16; ++j) acc[q][s][j] = 0.f;
    for (int i = 0; i < 64; ++i) {
        float wa[9], wb[9];
        #pragma unroll
        for (int r = 0; r < 9; ++r) { wa[r] = w1[(ca*64+i)*9 + r]; wb[r] = w1[(cb*64+i)*9 + r]; }
        #pragma unroll
        for (int q = 0; q < 4; ++q) {
            const float* xv = lds + (half*4 + q)*1024 + i*16;
            float xr[16];
            #pragma unroll
            for (int j4 = 0; j4 < 4; ++j4) {
                const float4 v = *reinterpret_cast<const float4*>(xv + 4*j4);
                xr[4*j4+0]=v.x; xr[4*j4+1]=v.y; xr[4*j4+2]=v.z; xr[4*j4+3]=v.w;
            }
            #pragma unroll
            for (int e = 0; e < 8; ++e) {
                const int ge = GE[e];
                const float xe = xr[2*e], xo = xr[2*e+1];
                acc[q][0][2*e]   += wa[ge]   * xe;
                acc[q][0][2*e+1] += wa[ge+1] * xo;
                acc[q][0][2*e+1] += wa[ge+5] * xe;
                acc[q][1][2*e]   += wb[ge]   * xe;
                acc[q][1][2*e+1] += wb[ge+1] * xo;
                acc[q][1][2*e+1] += wb[ge+5] * xe;
            }
        }
    }
    {
        const float ba = b1[ca], bb = b1[cb];
        #pragma unroll
        for (int q = 0; q < 4; ++q) { acc[q][0][0] += ba; acc[q][1][0] += bb; }
    }
    __syncthreads();
    #pragma unroll
    for (int q = 0; q < 4; ++q) {
        float prod[16];
        #pragma unroll
        for (int j = 0; j < 16; ++j) prod[j] = 0.f;
        if (c < 64) {
            #pragma unroll
            for (int A = 0; A < 16; ++A)
                #pragma unroll
                for (int B = 0; B < 16; ++B)
                    if (TB.gp[A][B] != 0.f)
                        prod[A ^ B] += TB.gp[A][B] * acc[q][0][A] * acc[q][1][B];
        } else {
            #pragma unroll
            for (int A = 0; A < 16; ++A)
                #pragma unroll
                for (int B = 0; B < 16; ++B)
                    if (TB.jn[A][B] != 0.f)
                        prod[A & B] += TB.jn[A][B] * acc[q][0][A] * acc[q][1][B];
            const float rp = lrefs[half*4 + q];
            #pragma unroll
            for (int j = 0; j < 16; ++j) prod[j] *= rp;
        }
        const int pos = half*4 + q;
        #pragma unroll
        for (int j4 = 0; j4 < 4; ++j4)
            *reinterpret_cast<float4*>(&lds[(pos*4 + j4)*512 + c*4]) =
                make_float4(prod[4*j4], prod[4*j4+1], prod[4*j4+2], prod[4*j4+3]);
    }
    __syncthreads();
    const int o    = t & 63;
    const int slot = t >> 6;
    float oacc[2][16];
    #pragma unroll
    for (int e2 = 0; e2 < 2; ++e2)
        #pragma unroll
        for (int j = 0; j < 16; ++j) oacc[e2][j] = 0.f;
    for (int i = 0; i < 128; ++i) {
        float wv[9];
        #pragma unroll
        for (int r = 0; r < 9; ++r) wv[r] = w2[(o*128+i)*9 + r];
        #pragma unroll
        for (int e2 = 0; e2 < 2; ++e2) {
            const int pos = slot*2 + e2;
            float xr[16];
            #pragma unroll
            for (int j4 = 0; j4 < 4; ++j4) {
                const float4 v = *reinterpret_cast<const float4*>(&lds[(pos*4 + j4)*512 + i*4]);
                xr[4*j4+0]=v.x; xr[4*j4+1]=v.y; xr[4*j4+2]=v.z; xr[4*j4+3]=v.w;
            }
            #pragma unroll
            for (int e = 0; e < 8; ++e) {
                const int ge = GE[e];
                oacc[e2][2*e]   += wv[ge]   * xr[2*e];
                oacc[e2][2*e+1] += wv[ge+1] * xr[2*e+1];
                oacc[e2][2*e+1] += wv[ge+5] * xr[2*e];
            }
        }
    }
    {
        const float bo = b2[o];
        #pragma unroll
        for (int e2 = 0; e2 < 2; ++e2) {
            oacc[e2][0] += bo;
            const int pos = p0 + slot*2 + e2;
            float* og = out + (size_t)pos*1024 + o*16;
            #pragma unroll
            for (int j4 = 0; j4 < 4; ++j4)
                *reinterpret_cast<float4*>(og + 4*j4) =
                    make_float4(oacc[e2][4*j4], oacc[e2][4*j4+1],
                                oacc[e2][4*j4+2], oacc[e2][4*j4+3]);
        }
    }
}

extern "C" void kernel_launch(void* const* d_in, const int* in_sizes, int n_in,
                              void* d_out, int out_size, void* d_ws, size_t ws_size,
                              hipStream_t stream)
{
    const float* x  = (const float*)d_in[0];
    const float* rf = (const float*)d_in[1];
    const float* w1 = (const float*)d_in[2];
    const float* b1 = (const float*)d_in[3];
    const float* w2 = (const float*)d_in[4];
    const float* b2 = (const float*)d_in[5];
    float* out = (float*)d_out;

    const size_t need = (size_t)(W1C_ELEMS + W2C_ELEMS)*2 + (H_ELEMS + O2_ELEMS)*2;
    if (ws_size >= need) {
        unsigned short* w1c = (unsigned short*)d_ws;
        unsigned short* w2c = w1c + W1C_ELEMS;
        unsigned short* hG  = w2c + W2C_ELEMS;
        unsigned short* o2G = hG + H_ELEMS;
        prep_w_c<<<(W1C_ELEMS + W2C_ELEMS)/256, 256, 0, stream>>>(w1, w2, w1c, w2c);
        for (int q = 0; q < 4; ++q) {
            const int P0 = q * QP;
            k1_gemm<<<256, 512, 0, stream>>>(x, b1, w1c, hG, P0);
            k2_prod<<<256, 256, 0, stream>>>(hG, rf, o2G, P0);
            k3_gemm<<<1024, 256, 0, stream>>>(o2G, b2, w2c, out, P0);
        }
    } else {
        gb_fused_f32<<<2048, 256, 0, stream>>>(x, rf, w1, b1, w2, b2, out);
    }
}

// Round 16
// 168.771 us; speedup vs baseline: 1.7562x; 1.7562x over previous
//
#include <hip/hip_runtime.h>

// PGA G(3,0,1) GeometricBilinear — R16: R11 fused kernel + LDS overlay ->
// 2 blocks/CU. P=16384, CIN=64, 2H=256, H=128, COUT=64, 16 blades.
//
// R15 decomposition: even a clean de-fused GEMM (LDS-resident W, low regs)
// sits at ~40us/block-round with ALL pipes <7% -> the wall is exposed
// latency serialized through each block's phase chain, with 1 block/CU and
// nothing to overlap. R4 (the only 2-blocks/CU fused variant) was fastest
// per-work. Fix: overlay X1 (34.8KB, dead after products) with X2 (69.6KB)
// in one union buffer + one extra barrier -> LDS 105->69.7KB -> 2 blocks/CU,
// 4 waves/SIMD. All math/layout verbatim from verified R11:
//   X1[row=e*16+pos][272B rows] (k=s*64+i, byte s*128+i*2)
//   w1c[o][1536], w2c[o][3072] row-packed (prep_w_c verified R11)
//   MFMA A=W rows(=ch o), B=X1 cols(=pos); D: pos=ln? no: col ln.. (R11 map)
//   X2[row=e2*16+pos][544B rows] (k2=s*128+cc); EP rows 4112B.

namespace {

constexpr int popc4(int v){int c=0;while(v){c+=v&1;v>>=1;}return c;}
constexpr float sgnf(int a,int b){int s=0;a>>=1;while(a){s+=popc4(a&b);a>>=1;}return (s&1)?-1.f:1.f;}

struct Tabs { float gp[16][16]; float jn[16][16]; };
constexpr Tabs mk(){
    Tabs t{};
    for(int a=0;a<16;a++)for(int b=0;b<16;b++){
        t.gp[a][b] = (a&b&1) ? 0.f : sgnf(a,b);
        if((a|b)==15){
            const int k = a&b;
            t.jn[a][b] = sgnf(a,15^a)*sgnf(b,15^b)*sgnf(15^a,15^b)*sgnf(k,15^k);
        } else t.jn[a][b] = 0.f;
    }
    return t;
}
constexpr Tabs TB = mk();
constexpr int GE[8] = {0,1,1,2,1,2,2,3};  // f32 fallback

constexpr int BASE1(int j){ return (j>>1)*192 + ((j&1)?64:0); }
constexpr int BASE2(int j){ return (j>>1)*384 + ((j&1)?128:0); }
constexpr int W1C_ELEMS = 256*1536;
constexpr int W2C_ELEMS = 64*3072;
constexpr int X1_STRIDE = 272;
constexpr int X2_STRIDE = 544;
constexpr int EP_STRIDE = 4112;
constexpr int U_BYTES   = 128*X2_STRIDE;   // 69632: X1 (34816) and X2/EP overlay

typedef short bf16x8 __attribute__((ext_vector_type(8)));
typedef float f32x4  __attribute__((ext_vector_type(4)));

__device__ inline unsigned short f2bf(float f){
    unsigned int u = __float_as_uint(f);
    u = u + 0x7fffu + ((u >> 16) & 1u);
    return (unsigned short)(u >> 16);
}
__device__ inline unsigned pack2(float a, float b){
    return (unsigned)f2bf(a) | ((unsigned)f2bf(b) << 16);
}

} // namespace

// ---------------- prep (verified R11): w1c[o][1536], w2c[o][3072] ------------
__global__ void prep_w_c(const float* __restrict__ w1, const float* __restrict__ w2,
                         unsigned short* __restrict__ w1c, unsigned short* __restrict__ w2c)
{
    int idx = blockIdx.x * 256 + threadIdx.x;
    if (idx < W1C_ELEMS) {
        const int o = idx / 1536, r = idx - o*1536;
        const int p = r / 192, q = r - p*192;
        float v;
        if (q < 64) {
            v = w1[(o*64 + q)*9 + popc4(2*p)];
        } else {
            const int j = 2*p + 1, k = q - 64, g = popc4(j);
            v = (k < 64) ? w1[(o*64 + k)*9 + g + 4]
                         : w1[(o*64 + (k - 64))*9 + g];
        }
        w1c[idx] = f2bf(v);
    } else {
        idx -= W1C_ELEMS;
        if (idx < W2C_ELEMS) {
            const int o = idx / 3072, r = idx - o*3072;
            const int p = r / 384, q = r - p*384;
            float v;
            if (q < 128) {
                v = w2[(o*128 + q)*9 + popc4(2*p)];
            } else {
                const int j = 2*p + 1, k = q - 128, g = popc4(j);
                v = (k < 128) ? w2[(o*128 + k)*9 + g + 4]
                              : w2[(o*128 + (k - 128))*9 + g];
            }
            w2c[idx] = f2bf(v);
        }
    }
}

// ---------------- fused kernel: 1024 blocks x 512 thr, 2 blocks/CU -----------
__global__ __launch_bounds__(512, 2) void gb_mfma(
    const float* __restrict__ x, const float* __restrict__ ref,
    const float* __restrict__ b1, const float* __restrict__ b2,
    const unsigned short* __restrict__ w1c, const unsigned short* __restrict__ w2c,
    float* __restrict__ out)
{
    __shared__ __attribute__((aligned(16))) char U[U_BYTES];   // X1 | X2 | EP overlay
    __shared__ float lref[16];

    const int t   = threadIdx.x;
    const int bid = blockIdx.x;
    const int w   = t >> 6;
    const int l   = t & 63;
    const int ln  = l & 15;
    const int lh  = l >> 4;
    const int p0  = bid * 16;

    const int st  = w >> 2;
    const int grp = w & 3;
    const int f0  = (st == 0) ? grp : grp + 8;

    const unsigned short* pA = w1c + (f0*16 + ln)*1536;
    const unsigned short* pB = w1c + ((f0+4)*16 + ln)*1536;
    const unsigned short* pC = w2c + (grp*16 + ln)*3072;
    const int vX1 = ln*X1_STRIDE + lh*16;
    const int vX2 = ln*X2_STRIDE + lh*16;
    const int vX2w = ln*X2_STRIDE + w*32 + lh*8;
    const int vEp  = ln*EP_STRIDE + grp*1024 + lh*256 + st*32;

    // ---- stage X1 (verified R11) ----
    {
        const int spos = t >> 5;
        const int si0  = (t & 31) * 2;
        const float* gsrc = x + ((long)(p0 + spos))*1024 + si0*16;
        float4 v[8];
        #pragma unroll
        for (int a = 0; a < 8; ++a) v[a] = *(const float4*)(gsrc + a*4);
        char* base = U + spos*X1_STRIDE + si0*2;
        #pragma unroll
        for (int b = 0; b < 16; ++b) {
            const int e = b >> 1, s = b & 1;
            const float va = ((const float*)&v[b>>2])[b&3];
            const float vb = ((const float*)&v[4 + (b>>2)])[b&3];
            *(unsigned*)(base + e*16*X1_STRIDE + s*128) = pack2(va, vb);
        }
        if (t < 16) lref[t] = ref[((long)(p0 + t))*16 + 15];
    }
    __syncthreads();

    // ---- phase 1: left GEMM ----
    f32x4 left[16];
    #pragma unroll
    for (int j = 0; j < 16; ++j) left[j] = (f32x4)0.f;
    #pragma unroll
    for (int j = 0; j < 16; ++j) {
        const int e = j >> 1, nkf = (j & 1) ? 4 : 2;
        #pragma unroll
        for (int kf = 0; kf < nkf; ++kf) {
            const bf16x8 a  = *(const bf16x8*)(pA + BASE1(j) + kf*32 + lh*8);
            const bf16x8 bx = *(const bf16x8*)(U + vX1 + e*16*X1_STRIDE + kf*64);
            left[j] = __builtin_amdgcn_mfma_f32_16x16x32_bf16(a, bx, left[j], 0, 0, 0);
        }
    }
    #pragma unroll
    for (int r = 0; r < 4; ++r) left[0][r] += b1[f0*16 + lh*4 + r];

    // ---- right blades streamed + product columns ----
    f32x4 prod[16];
    #pragma unroll
    for (int j = 0; j < 16; ++j) prod[j] = (f32x4)0.f;
    #pragma unroll
    for (int j = 0; j < 16; ++j) {
        const int e = j >> 1, nkf = (j & 1) ? 4 : 2;
        f32x4 right = (f32x4)0.f;
        #pragma unroll
        for (int kf = 0; kf < nkf; ++kf) {
            const bf16x8 a  = *(const bf16x8*)(pB + BASE1(j) + kf*32 + lh*8);
            const bf16x8 bx = *(const bf16x8*)(U + vX1 + e*16*X1_STRIDE + kf*64);
            right = __builtin_amdgcn_mfma_f32_16x16x32_bf16(a, bx, right, 0, 0, 0);
        }
        if (j == 0) {
            #pragma unroll
            for (int r = 0; r < 4; ++r) right[r] += b1[(f0+4)*16 + lh*4 + r];
        }
        if (st == 0) {
            #pragma unroll
            for (int A = 0; A < 16; ++A) {
                if (TB.gp[A][j] > 0.f)      prod[A ^ j] += left[A] * right;
                else if (TB.gp[A][j] < 0.f) prod[A ^ j] -= left[A] * right;
            }
        } else {
            #pragma unroll
            for (int A = 0; A < 16; ++A) {
                if (TB.jn[A][j] > 0.f)      prod[A & j] += left[A] * right;
                else if (TB.jn[A][j] < 0.f) prod[A & j] -= left[A] * right;
            }
        }
    }
    if (st == 1) {
        const float rv = lref[ln];
        #pragma unroll
        for (int j = 0; j < 16; ++j) prod[j] *= rv;
    }

    __syncthreads();   // NEW (R16): all X1 reads done; U becomes X2

    // ---- write prod -> X2 (verified R11 layout) ----
    #pragma unroll
    for (int e2 = 0; e2 < 8; ++e2)
        #pragma unroll
        for (int s = 0; s < 2; ++s)
            #pragma unroll
            for (int rp = 0; rp < 4; rp += 2)
                *(unsigned*)(U + vX2w + e2*16*X2_STRIDE + s*256 + rp*2) =
                    pack2(prod[2*e2 + s][rp], prod[2*e2 + s][rp + 1]);
    __syncthreads();

    // ---- phase 2 (verified R11) ----
    f32x4 acc2[8];
    #pragma unroll
    for (int jj = 0; jj < 8; ++jj) acc2[jj] = (f32x4)0.f;
    #pragma unroll
    for (int jj = 0; jj < 8; ++jj) {
        const int j2 = st*8 + jj;
        const int e2 = j2 >> 1, nkf = (j2 & 1) ? 8 : 4;
        #pragma unroll
        for (int kf = 0; kf < nkf; ++kf) {
            const bf16x8 a  = *(const bf16x8*)(pC + BASE2(j2) + kf*32 + lh*8);
            const bf16x8 bx = *(const bf16x8*)(U + vX2 + e2*16*X2_STRIDE + kf*64);
            acc2[jj] = __builtin_amdgcn_mfma_f32_16x16x32_bf16(a, bx, acc2[jj], 0, 0, 0);
        }
    }
    if (st == 0) {
        #pragma unroll
        for (int r = 0; r < 4; ++r) acc2[0][r] += b2[grp*16 + lh*4 + r];
    }
    __syncthreads();   // X2 reads done; U becomes EP

    // ---- epilogue (verified R11, padded rows) ----
    #pragma unroll
    for (int r = 0; r < 4; ++r) {
        *(float4*)(U + vEp + r*64) =
            make_float4(acc2[0][r], acc2[1][r], acc2[2][r], acc2[3][r]);
        *(float4*)(U + vEp + r*64 + 16) =
            make_float4(acc2[4][r], acc2[5][r], acc2[6][r], acc2[7][r]);
    }
    __syncthreads();
    {
        #pragma unroll
        for (int it = 0; it < 8; ++it) {
            const int idx = it*512 + t;
            const int pos = idx >> 8, off = idx & 255;
            const float4 vv = *(const float4*)(U + pos*EP_STRIDE + off*16);
            *(float4*)(out + ((long)(p0 + pos))*1024 + off*4) = vv;
        }
    }
}

// ---------------- fp32 last-resort fallback (verified R3) --------------------
__global__ __launch_bounds__(256, 1) void gb_fused_f32(
    const float* __restrict__ x, const float* __restrict__ ref,
    const float* __restrict__ w1, const float* __restrict__ b1,
    const float* __restrict__ w2, const float* __restrict__ b2,
    float* __restrict__ out)
{
    __shared__ float lds[16384];
    __shared__ float lrefs[8];
    const int t = threadIdx.x;
    const int p0 = blockIdx.x * 8;
    {
        const float4* xg = reinterpret_cast<const float4*>(x) + (size_t)p0 * 256;
        float4* xl = reinterpret_cast<float4*>(lds);
        #pragma unroll
        for (int r = 0; r < 8; ++r) xl[r*256 + t] = xg[r*256 + t];
        if (t < 8) lrefs[t] = ref[(p0 + t)*16 + 15];
    }
    __syncthreads();
    const int c    = t & 127;
    const int half = t >> 7;
    const int ca   = (c < 64) ? c : (c + 64);
    const int cb   = ca + 64;
    float acc[4][2][16];
    #pragma unroll
    for (int q = 0; q < 4; ++q)
        #pragma unroll
        for (int s = 0; s < 2; ++s)
            #pragma unroll
            for (int j = 0; j < 16; ++j) acc[q][s][j] = 0.f;
    for (int i = 0; i < 64; ++i) {
        float wa[9], wb[9];
        #pragma unroll
        for (int r = 0; r < 9; ++r) { wa[r] = w1[(ca*64+i)*9 + r]; wb[r] = w1[(cb*64+i)*9 + r]; }
        #pragma unroll
        for (int q = 0; q < 4; ++q) {
            const float* xv = lds + (half*4 + q)*1024 + i*16;
            float xr[16];
            #pragma unroll
            for (int j4 = 0; j4 < 4; ++j4) {
                const float4 v = *reinterpret_cast<const float4*>(xv + 4*j4);
                xr[4*j4+0]=v.x; xr[4*j4+1]=v.y; xr[4*j4+2]=v.z; xr[4*j4+3]=v.w;
            }
            #pragma unroll
            for (int e = 0; e < 8; ++e) {
                const int ge = GE[e];
                const float xe = xr[2*e], xo = xr[2*e+1];
                acc[q][0][2*e]   += wa[ge]   * xe;
                acc[q][0][2*e+1] += wa[ge+1] * xo;
                acc[q][0][2*e+1] += wa[ge+5] * xe;
                acc[q][1][2*e]   += wb[ge]   * xe;
                acc[q][1][2*e+1] += wb[ge+1] * xo;
                acc[q][1][2*e+1] += wb[ge+5] * xe;
            }
        }
    }
    {
        const float ba = b1[ca], bb = b1[cb];
        #pragma unroll
        for (int q = 0; q < 4; ++q) { acc[q][0][0] += ba; acc[q][1][0] += bb; }
    }
    __syncthreads();
    #pragma unroll
    for (int q = 0; q < 4; ++q) {
        float prod[16];
        #pragma unroll
        for (int j = 0; j < 16; ++j) prod[j] = 0.f;
        if (c < 64) {
            #pragma unroll
            for (int A = 0; A < 16; ++A)
                #pragma unroll
                for (int B = 0; B < 16; ++B)
                    if (TB.gp[A][B] != 0.f)
                        prod[A ^ B] += TB.gp[A][B] * acc[q][0][A] * acc[q][1][B];
        } else {
            #pragma unroll
            for (int A = 0; A < 16; ++A)
                #pragma unroll
                for (int B = 0; B < 16; ++B)
                    if (TB.jn[A][B] != 0.f)
                        prod[A & B] += TB.jn[A][B] * acc[q][0][A] * acc[q][1][B];
            const float rp = lrefs[half*4 + q];
            #pragma unroll
            for (int j = 0; j < 16; ++j) prod[j] *= rp;
        }
        const int pos = half*4 + q;
        #pragma unroll
        for (int j4 = 0; j4 < 4; ++j4)
            *reinterpret_cast<float4*>(&lds[(pos*4 + j4)*512 + c*4]) =
                make_float4(prod[4*j4], prod[4*j4+1], prod[4*j4+2], prod[4*j4+3]);
    }
    __syncthreads();
    const int o    = t & 63;
    const int slot = t >> 6;
    float oacc[2][16];
    #pragma unroll
    for (int e2 = 0; e2 < 2; ++e2)
        #pragma unroll
        for (int j = 0; j < 16; ++j) oacc[e2][j] = 0.f;
    for (int i = 0; i < 128; ++i) {
        float wv[9];
        #pragma unroll
        for (int r = 0; r < 9; ++r) wv[r] = w2[(o*128+i)*9 + r];
        #pragma unroll
        for (int e2 = 0; e2 < 2; ++e2) {
            const int pos = slot*2 + e2;
            float xr[16];
            #pragma unroll
            for (int j4 = 0; j4 < 4; ++j4) {
                const float4 v = *reinterpret_cast<const float4*>(&lds[(pos*4 + j4)*512 + i*4]);
                xr[4*j4+0]=v.x; xr[4*j4+1]=v.y; xr[4*j4+2]=v.z; xr[4*j4+3]=v.w;
            }
            #pragma unroll
            for (int e = 0; e < 8; ++e) {
                const int ge = GE[e];
                oacc[e2][2*e]   += wv[ge]   * xr[2*e];
                oacc[e2][2*e+1] += wv[ge+1] * xr[2*e+1];
                oacc[e2][2*e+1] += wv[ge+5] * xr[2*e];
            }
        }
    }
    {
        const float bo = b2[o];
        #pragma unroll
        for (int e2 = 0; e2 < 2; ++e2) {
            oacc[e2][0] += bo;
            const int pos = p0 + slot*2 + e2;
            float* og = out + (size_t)pos*1024 + o*16;
            #pragma unroll
            for (int j4 = 0; j4 < 4; ++j4)
                *reinterpret_cast<float4*>(og + 4*j4) =
                    make_float4(oacc[e2][4*j4], oacc[e2][4*j4+1],
                                oacc[e2][4*j4+2], oacc[e2][4*j4+3]);
        }
    }
}

extern "C" void kernel_launch(void* const* d_in, const int* in_sizes, int n_in,
                              void* d_out, int out_size, void* d_ws, size_t ws_size,
                              hipStream_t stream)
{
    const float* x  = (const float*)d_in[0];
    const float* rf = (const float*)d_in[1];
    const float* w1 = (const float*)d_in[2];
    const float* b1 = (const float*)d_in[3];
    const float* w2 = (const float*)d_in[4];
    const float* b2 = (const float*)d_in[5];
    float* out = (float*)d_out;

    const size_t need = (size_t)(W1C_ELEMS + W2C_ELEMS) * sizeof(unsigned short);
    if (ws_size >= need) {
        unsigned short* w1c = (unsigned short*)d_ws;
        unsigned short* w2c = w1c + W1C_ELEMS;
        prep_w_c<<<(W1C_ELEMS + W2C_ELEMS)/256, 256, 0, stream>>>(w1, w2, w1c, w2c);
        gb_mfma<<<1024, 512, 0, stream>>>(x, rf, b1, b2, w1c, w2c, out);
    } else {
        gb_fused_f32<<<2048, 256, 0, stream>>>(x, rf, w1, b1, w2, b2, out);
    }
}